// Round 6
// baseline (425.566 us; speedup 1.0000x reference)
//
#include <hip/hip_runtime.h>
#include <hip/hip_bf16.h>
#include <hip/hip_fp16.h>

// QRNN: B=16, S=2048, D=1024, H=1024.  Inputs fp32, outputs fp32.
// Phase 0: convert X, W -> fp16 in ws
// Phase 1: GEMM G[rows][3072] = X16 @ W16^T + b (fp16 MFMA, fp32 acc, fp16 store)
// Phase 2: chunked linear scan h_t = z_t f_t + (1-f_t) h_{t-1}  (32 chunks x 64), 3 passes
// Slab-adaptive on ws_size; per-batch ~17.2 MB + W16 6.3 MB.

#define BB 16
#define SS 2048
#define DD 1024
#define HH 1024
#define N3 3072
#define CHUNK 64
#define NC (SS/CHUNK)    // 32

typedef _Float16 f16x8 __attribute__((ext_vector_type(8)));
typedef float    f32x4 __attribute__((ext_vector_type(4)));

__device__ __forceinline__ float sigm_f(float x) {
    return 1.0f / (1.0f + __expf(-x));
}
__device__ __forceinline__ float tanh_f(float x) {
    float ax = fabsf(x);
    float e  = __expf(2.0f * ax);
    float r  = 1.0f - 2.0f / (e + 1.0f);
    return copysignf(r, x);
}

// ---------------- Phase 0: fp32 -> fp16 convert (8 elems/thread) -------------
__global__ __launch_bounds__(256) void cvt_f32_f16(
    const float* __restrict__ src, __half* __restrict__ dst, int n8)
{
    int i = blockIdx.x * 256 + threadIdx.x;
    if (i >= n8) return;
    const float4* s = (const float4*)src + (size_t)i * 2;
    float4 a = s[0], b = s[1];
    f16x8 v;
    v[0] = (_Float16)a.x; v[1] = (_Float16)a.y; v[2] = (_Float16)a.z; v[3] = (_Float16)a.w;
    v[4] = (_Float16)b.x; v[5] = (_Float16)b.y; v[6] = (_Float16)b.z; v[7] = (_Float16)b.w;
    *((f16x8*)dst + i) = v;
}

// ---------------- GEMM: m97 structure (128x128 tile, BK=32, 4 waves) ---------
__global__ __launch_bounds__(256) void gemm_gates(
    const __half* __restrict__ Xs,      // [rows][1024] fp16 (slab-local)
    const __half* __restrict__ W16,     // [3072][1024] fp16
    const float*  __restrict__ bias,    // [3072] fp32
    __half* __restrict__ G)             // [rows][3072] fp16
{
    __shared__ __half As[128 * 32] __attribute__((aligned(16)));
    __shared__ __half Bs[128 * 32] __attribute__((aligned(16)));

    const int t  = threadIdx.x;
    const int w  = t >> 6;
    const int l  = t & 63;
    const int m0 = blockIdx.y * 128;
    const int n0 = blockIdx.x * 128;
    const int wm = w >> 1;
    const int wn = w & 1;

    f32x4 acc[4][4];
    #pragma unroll
    for (int m = 0; m < 4; ++m)
        #pragma unroll
        for (int n = 0; n < 4; ++n)
            acc[m][n] = f32x4{0.f, 0.f, 0.f, 0.f};

    // staging: tile = 8 chunks of 1024B; wave w stages chunks {w, w+4}
    // chunk c, lane l -> row = c*16 + l/4, col elems = (l&3)*8; LDS dest linear
    const int c0 = w;
    const int c1 = w + 4;
    const int rA0 = c0 * 16 + (l >> 2);
    const int rA1 = c1 * 16 + (l >> 2);
    const int ck  = (l & 3) * 8;

    const __half* Xb = Xs + (size_t)m0 * DD;
    const __half* Wb = W16 + (size_t)n0 * DD;

    const int cl = l & 15;   // row-in-operand / col-in-C
    const int kg = l >> 4;   // k-group 0..3

    for (int k0 = 0; k0 < DD; k0 += 32) {
        __builtin_amdgcn_global_load_lds(
            (const __attribute__((address_space(1))) void*)(Xb + (size_t)rA0 * DD + k0 + ck),
            (__attribute__((address_space(3))) void*)((char*)As + c0 * 1024), 16, 0, 0);
        __builtin_amdgcn_global_load_lds(
            (const __attribute__((address_space(1))) void*)(Xb + (size_t)rA1 * DD + k0 + ck),
            (__attribute__((address_space(3))) void*)((char*)As + c1 * 1024), 16, 0, 0);
        __builtin_amdgcn_global_load_lds(
            (const __attribute__((address_space(1))) void*)(Wb + (size_t)rA0 * DD + k0 + ck),
            (__attribute__((address_space(3))) void*)((char*)Bs + c0 * 1024), 16, 0, 0);
        __builtin_amdgcn_global_load_lds(
            (const __attribute__((address_space(1))) void*)(Wb + (size_t)rA1 * DD + k0 + ck),
            (__attribute__((address_space(3))) void*)((char*)Bs + c1 * 1024), 16, 0, 0);
        __syncthreads();

        f16x8 a[4], b[4];
        const f16x8* Av = (const f16x8*)As;
        const f16x8* Bv = (const f16x8*)Bs;
        #pragma unroll
        for (int m = 0; m < 4; ++m)
            a[m] = Av[(wm * 64 + m * 16 + cl) * 4 + kg];
        #pragma unroll
        for (int n = 0; n < 4; ++n)
            b[n] = Bv[(wn * 64 + n * 16 + cl) * 4 + kg];

        #pragma unroll
        for (int m = 0; m < 4; ++m)
            #pragma unroll
            for (int n = 0; n < 4; ++n)
                acc[m][n] = __builtin_amdgcn_mfma_f32_16x16x32_f16(
                    a[m], b[n], acc[m][n], 0, 0, 0);
        __syncthreads();
    }

    // epilogue: C/D layout col = lane&15, row = (lane>>4)*4 + reg [m89-verified]
    #pragma unroll
    for (int n = 0; n < 4; ++n) {
        const int gcol = n0 + wn * 64 + n * 16 + cl;
        const float bv = bias[gcol];
        #pragma unroll
        for (int m = 0; m < 4; ++m) {
            const int grow0 = m0 + wm * 64 + m * 16 + kg * 4;
            #pragma unroll
            for (int i = 0; i < 4; ++i) {
                G[(size_t)(grow0 + i) * N3 + gcol] = __float2half(acc[m][n][i] + bv);
            }
        }
    }
}

// ---------------- Pass 1: per-chunk local scan -> (A, F) ---------------------
// h' = a + b*h with a = tanh(z)*sig(f), b = 1-sig(f); chunk composition:
// A = local scan end (h_in = 0), F = prod b.
__global__ __launch_bounds__(256) void scan_pass1(
    const __half* __restrict__ G,
    float* __restrict__ Ac, float* __restrict__ Fc)
{
    const int flat = blockIdx.x * 256 + threadIdx.x;
    const int h  = flat & (HH - 1);
    const int c  = (flat >> 10) & (NC - 1);
    const int lb = flat >> 15;

    const __half* g = G + (size_t)(lb * SS + c * CHUNK) * N3 + h;
    float A = 0.f, F = 1.f;
    for (int s = 0; s < CHUNK; ++s) {
        float z = __half2float(g[0]);
        float f = __half2float(g[HH]);
        g += N3;
        float ft = sigm_f(f);
        float fp = 1.f - ft;
        A = tanh_f(z) * ft + fp * A;
        F *= fp;
    }
    Ac[flat] = A;
    Fc[flat] = F;
}

// ---------------- Pass 2: sequential chunk combine, emit h_in + c_last -------
__global__ __launch_bounds__(256) void scan_pass2(
    const float* __restrict__ Ac, const float* __restrict__ Fc,
    float* __restrict__ Hin, float* __restrict__ c_last)
{
    const int flat = blockIdx.x * 256 + threadIdx.x;   // lb*HH + h
    const int lb = flat >> 10;
    const int h  = flat & (HH - 1);
    float hc = 0.f;
    for (int c = 0; c < NC; ++c) {
        const size_t idx = (size_t)(lb * NC + c) * HH + h;
        Hin[idx] = hc;
        hc = Ac[idx] + Fc[idx] * hc;
    }
    c_last[flat] = hc;
}

// ---------------- Pass 3: replay with correct h_in, fuse output gate ---------
__global__ __launch_bounds__(256) void scan_pass3(
    const __half* __restrict__ G, const float* __restrict__ Hin,
    float* __restrict__ out)
{
    const int flat = blockIdx.x * 256 + threadIdx.x;
    const int h  = flat & (HH - 1);
    const int c  = (flat >> 10) & (NC - 1);
    const int lb = flat >> 15;

    const __half* g = G + (size_t)(lb * SS + c * CHUNK) * N3 + h;
    float* o = out + (size_t)(lb * SS + c * CHUNK) * HH + h;
    float hc = Hin[flat];
    for (int s = 0; s < CHUNK; ++s) {
        float z  = __half2float(g[0]);
        float f  = __half2float(g[HH]);
        float og = __half2float(g[2 * HH]);
        g += N3;
        float ft = sigm_f(f);
        hc = tanh_f(z) * ft + (1.f - ft) * hc;
        *o = hc * sigm_f(og);
        o += HH;
    }
}

extern "C" void kernel_launch(void* const* d_in, const int* in_sizes, int n_in,
                              void* d_out, int out_size, void* d_ws, size_t ws_size,
                              hipStream_t stream) {
    // re-key inputs by element count for order safety
    const float* X    = (const float*)d_in[0];
    const float* W    = (const float*)d_in[1];
    const float* bias = (const float*)d_in[2];
    for (int i = 0; i < n_in && i < 3; ++i) {
        if      (in_sizes[i] == BB * SS * DD) X    = (const float*)d_in[i];
        else if (in_sizes[i] == N3 * DD)      W    = (const float*)d_in[i];
        else if (in_sizes[i] == N3)           bias = (const float*)d_in[i];
    }
    float* out = (float*)d_out;                           // [B,S,H] ++ [B,1,H] fp32
    float* c_last_base = out + (size_t)BB * SS * HH;

    // ws layout: W16 | X16(nb) | G(nb) | Ac/Fc/Hin(nb)
    const size_t w16_b   = (size_t)N3 * DD * sizeof(__half);          //  6.29 MB
    const size_t per_b_x = (size_t)SS * DD * sizeof(__half);          //  4.19 MB
    const size_t per_b_g = (size_t)SS * N3 * sizeof(__half);          // 12.58 MB
    const size_t per_b_s = (size_t)NC * HH * sizeof(float) * 3;       //  0.39 MB
    int nb = 1;
    for (int cand = BB; cand >= 1; --cand) {
        if (w16_b + (size_t)cand * (per_b_x + per_b_g + per_b_s) <= ws_size) {
            nb = cand; break;
        }
    }

    __half* W16 = (__half*)d_ws;
    __half* X16 = (__half*)((char*)W16 + w16_b);
    __half* G   = (__half*)((char*)X16 + (size_t)nb * per_b_x);
    float*  Ac  = (float*)((char*)G + (size_t)nb * per_b_g);
    float*  Fc  = Ac + (size_t)nb * NC * HH;
    float*  Hin = Fc + (size_t)nb * NC * HH;

    // W convert (once)
    {
        const int n8 = (N3 * DD) / 8;
        cvt_f32_f16<<<(n8 + 255) / 256, 256, 0, stream>>>(W, W16, n8);
    }

    for (int b0 = 0; b0 < BB; b0 += nb) {
        const int bs = (b0 + nb <= BB) ? nb : (BB - b0);

        const int n8x = (bs * SS * DD) / 8;
        cvt_f32_f16<<<(n8x + 255) / 256, 256, 0, stream>>>(
            X + (size_t)b0 * SS * DD, X16, n8x);

        dim3 gg(N3 / 128, bs * (SS / 128));
        gemm_gates<<<gg, 256, 0, stream>>>(X16, W16, bias, G);

        scan_pass1<<<(bs * NC * HH) / 256, 256, 0, stream>>>(G, Ac, Fc);
        scan_pass2<<<(bs * HH) / 256, 256, 0, stream>>>(Ac, Fc, Hin,
                                                        c_last_base + (size_t)b0 * HH);
        scan_pass3<<<(bs * NC * HH) / 256, 256, 0, stream>>>(G, Hin,
                                                             out + (size_t)b0 * SS * HH);
    }
}